// Round 1
// baseline (201.679 us; speedup 1.0000x reference)
//
#include <hip/hip_runtime.h>
#include <math.h>

// Capsule dynamic routing, MI355X. Round 6: unified per-iteration structure.
//   Every routing iteration i emits per-tile o-partials Op[b][tile][160]
//   (fold G through W in-block; o is linear in the per-tile G partials).
//   makeV folds Op -> o[b,j,:] -> V[b,j,k] = sum_d W[k,jd] o[j,d].
//   Route kernels stage the 64x128 u tile to LDS ONCE via global_load_lds
//   (linear dest + XOR-pre-swizzled source, c' = c ^ (r&7)), then both the
//   logits phase (row/thread, ds_read_b128) and the G phase (k-pair/lane,
//   ds_read_b64) read LDS conflict-free. u read 3x total (was 5x).
// Chain: iter0(uniform c) -> makeV -> route -> makeV -> route -> squash.

#define BATCH 64
#define NN    2048
#define KD    128
#define JCAP  10
#define DCAP  16
#define JDIM  160
#define EPSQ  1e-7f
#define NT    32      // tiles of TROW rows
#define TROW  64

// ws layout (floats): Op[64][32][160] @0 ; V[64][10][128] @327680
#define WS_OP 0
#define WS_V  (BATCH * NT * JDIM)

__device__ __forceinline__ void gload16(const float* g, float4* l) {
  __builtin_amdgcn_global_load_lds(
      (const __attribute__((address_space(1))) void*)g,
      (__attribute__((address_space(3))) void*)l, 16, 0, 0);
}

// ---- K1: iteration 0 (c uniform 0.1): per-tile colsum -> fold through W ----
__global__ __launch_bounds__(256) void f_iter0(const float* __restrict__ u,
                                               const float* __restrict__ W,
                                               float* __restrict__ Op) {
  const int b = blockIdx.y, tile = blockIdx.x, t = threadIdx.x;
  __shared__ __align__(16) float4 red[256];
  __shared__ float S_s[KD];
  const int c = t & 31, rg = t >> 5;        // 8 row-groups x 8 rows
  const float* p = u + (((size_t)(b * NN + tile * TROW + rg * 8)) << 7) + (c << 2);
  float4 a = make_float4(0.f, 0.f, 0.f, 0.f);
#pragma unroll
  for (int r = 0; r < 8; ++r) {
    const float4 w4 = *(const float4*)(p + ((size_t)r << 7));
    a.x += w4.x; a.y += w4.y; a.z += w4.z; a.w += w4.w;
  }
  red[t] = a;
  __syncthreads();
  if (t < 32) {
    float4 s4 = red[t];
#pragma unroll
    for (int g = 1; g < 8; ++g) {
      const float4 w4 = red[g * 32 + t];
      s4.x += w4.x; s4.y += w4.y; s4.z += w4.z; s4.w += w4.w;
    }
    s4.x *= 0.1f; s4.y *= 0.1f; s4.z *= 0.1f; s4.w *= 0.1f;
    *(float4*)&S_s[t * 4] = s4;              // G[j][k] = 0.1*S[k] for all j
  }
  __syncthreads();
  if (t < JDIM) {
    float acc = 0.f;
#pragma unroll 4
    for (int k = 0; k < KD; ++k) acc += S_s[k] * W[k * JDIM + t];
    Op[((size_t)(b * NT) + tile) * JDIM + t] = acc;
  }
}

// ---- K2/K4: fold Op -> o[b,j,:] -> V[b,j,:] ; grid (10, 64), 128 thr ----
__global__ __launch_bounds__(128) void f_makeV(const float* __restrict__ Op,
                                               const float* __restrict__ W,
                                               float* __restrict__ V) {
  const int j = blockIdx.x, b = blockIdx.y, t = threadIdx.x;
  __shared__ float o_s[DCAP];
  if (t < DCAP) {
    float s = 0.f;
    const float* p = Op + (size_t)b * NT * JDIM + j * DCAP + t;
#pragma unroll
    for (int tl = 0; tl < NT; ++tl) s += p[tl * JDIM];
    o_s[t] = s;
  }
  __syncthreads();
  const float* wp = W + t * JDIM + j * DCAP;   // t = k (0..127)
  float acc = 0.f;
#pragma unroll
  for (int d = 0; d < DCAP; ++d) acc += wp[d] * o_s[d];
  V[((size_t)(b * JCAP + j) << 7) + t] = acc;
}

// ---- K3/K5: full routing iteration: logits -> softmax -> G -> fold W ----
__global__ __launch_bounds__(256) void f_route(const float* __restrict__ u,
                                               const float* __restrict__ V,
                                               const float* __restrict__ W,
                                               float* __restrict__ Op) {
  const int b = blockIdx.y, tile = blockIdx.x, t = threadIdx.x;
  const int r0 = tile * TROW;
  __shared__ __align__(16) float4 u4[TROW * 32];   // 32 KB, XOR-swizzled
  __shared__ __align__(16) float Cs[JCAP][TROW];   // 2.5 KB
  __shared__ __align__(16) float Gp[4 * JCAP * KD]; // 20 KB (phase1: Pl[4][10][64])

  // stage u tile -> LDS: linear dest (wave base + lane*16), swizzled source
  {
    const float* ub = u + (((size_t)(b * NN + r0)) << 7);
    const int wbase = t & 192;                     // wave base within block
#pragma unroll
    for (int p = 0; p < 8; ++p) {
      const int s = p * 256 + t;
      const int r = s >> 5, csl = s & 31;
      const int c = csl ^ (r & 7);                 // involution
      gload16(ub + (((size_t)r) << 7) + (c << 2), &u4[p * 256 + wbase]);
    }
  }
  __syncthreads();   // drains vmcnt

  // phase 1: logits[j][r] = u[r,:].V[j,:]  (row = t&63, k-quarter = wave)
  {
    const int r = t & 63;
    const int q = __builtin_amdgcn_readfirstlane(t >> 6);  // SGPR -> s_loads of V
    const float* vb = V + (((size_t)(b * JCAP)) << 7) + (q << 5);
    float acc[JCAP];
#pragma unroll
    for (int j = 0; j < JCAP; ++j) acc[j] = 0.f;
#pragma unroll
    for (int c4 = 0; c4 < 8; ++c4) {
      const float4 uu = u4[(r << 5) + ((q * 8 + c4) ^ (r & 7))];
#pragma unroll
      for (int j = 0; j < JCAP; ++j) {
        const float4 vv = *(const float4*)(vb + (j << 7) + (c4 << 2));
        acc[j] += uu.x * vv.x + uu.y * vv.y + uu.z * vv.z + uu.w * vv.w;
      }
    }
    float* Pl = Gp;                                // [4][10][64] partial logits
#pragma unroll
    for (int j = 0; j < JCAP; ++j) Pl[(q * JCAP + j) * 64 + r] = acc[j];
  }
  __syncthreads();
  if (t < TROW) {                                  // softmax over j (1 wave)
    const float* Pl = Gp;
    float lg[JCAP];
    float m = -1e30f;
#pragma unroll
    for (int j = 0; j < JCAP; ++j) {
      const float s = Pl[j * 64 + t] + Pl[(JCAP + j) * 64 + t]
                    + Pl[(2 * JCAP + j) * 64 + t] + Pl[(3 * JCAP + j) * 64 + t];
      lg[j] = s; m = fmaxf(m, s);
    }
    float ssum = 0.f;
#pragma unroll
    for (int j = 0; j < JCAP; ++j) { lg[j] = __expf(lg[j] - m); ssum += lg[j]; }
    const float inv = 1.f / ssum;
#pragma unroll
    for (int j = 0; j < JCAP; ++j) Cs[j][t] = lg[j] * inv;
  }
  __syncthreads();

  // phase 2: G[j][k] partials; wave = 16 rows, lane = k-pair (LDS b64 reads)
  {
    const int w = t >> 6, lane = t & 63;
    const int rw = w * 16;
    const int chalf = lane >> 1, cin = (lane & 1) << 1;  // k = 2*lane
    float g0[JCAP], g1[JCAP];
#pragma unroll
    for (int j = 0; j < JCAP; ++j) { g0[j] = 0.f; g1[j] = 0.f; }
    for (int rc = 0; rc < 16; rc += 4) {
      float ua[4], uc[4];
#pragma unroll
      for (int qq = 0; qq < 4; ++qq) {
        const int r = rw + rc + qq;
        const float2 uu2 =
            *(const float2*)((const float*)&u4[(r << 5) + (chalf ^ (r & 7))] + cin);
        ua[qq] = uu2.x; uc[qq] = uu2.y;
      }
#pragma unroll
      for (int j = 0; j < JCAP; ++j) {
        const float4 c4v = *(const float4*)&Cs[j][rw + rc];
        g0[j] += c4v.x * ua[0] + c4v.y * ua[1] + c4v.z * ua[2] + c4v.w * ua[3];
        g1[j] += c4v.x * uc[0] + c4v.y * uc[1] + c4v.z * uc[2] + c4v.w * uc[3];
      }
    }
#pragma unroll
    for (int j = 0; j < JCAP; ++j)
      *(float2*)&Gp[(w * JCAP + j) * KD + 2 * lane] = make_float2(g0[j], g1[j]);
  }
  __syncthreads();
  // fold 4 wave-partials (disjoint i per thread -> race-free in-place)
  for (int i = t; i < JCAP * KD; i += 256)
    Gp[i] += Gp[JCAP * KD + i] + Gp[2 * JCAP * KD + i] + Gp[3 * JCAP * KD + i];
  __syncthreads();
  // fold G through W -> per-tile o partials (k rotated by 3j: bank-spread)
  if (t < JDIM) {
    const int j = t >> 4;
    const float* gj = Gp + j * KD;
    float acc = 0.f;
#pragma unroll 4
    for (int kk = 0; kk < KD; ++kk) {
      const int k = (kk + 3 * j) & 127;
      acc += gj[k] * W[k * JDIM + t];
    }
    Op[((size_t)(b * NT) + tile) * JDIM + t] = acc;
  }
}

// ---- K6: fold Op partials, squash, store ----
__global__ __launch_bounds__(192) void f_squash(const float* __restrict__ Op,
                                                float* __restrict__ out) {
  const int b = blockIdx.x, t = threadIdx.x;
  __shared__ float o_s[JDIM];
  __shared__ float sc[JCAP];
  if (t < JDIM) {
    float s = 0.f;
    const float* p = Op + (size_t)b * NT * JDIM + t;
#pragma unroll
    for (int tl = 0; tl < NT; ++tl) s += p[tl * JDIM];
    o_s[t] = s;
  }
  __syncthreads();
  if (t < JCAP) {
    float s2 = 0.f;
#pragma unroll
    for (int d = 0; d < DCAP; ++d) { const float x = o_s[t * DCAP + d]; s2 += x * x; }
    sc[t] = s2 / ((1.f + s2) * sqrtf(s2 + EPSQ));
  }
  __syncthreads();
  if (t < JDIM) out[b * JDIM + t] = o_s[t] * sc[t >> 4];
}

extern "C" void kernel_launch(void* const* d_in, const int* in_sizes, int n_in,
                              void* d_out, int out_size, void* d_ws, size_t ws_size,
                              hipStream_t stream) {
  const float* u = (const float*)d_in[0];   // (64,2048,128) fp32
  const float* W = (const float*)d_in[1];   // (128,160) fp32
  float* out = (float*)d_out;               // (64,10,16) fp32
  float* ws  = (float*)d_ws;

  float* Op = ws + WS_OP;
  float* V  = ws + WS_V;
  f_iter0 <<<dim3(NT, BATCH), 256, 0, stream>>>(u, W, Op);
  f_makeV <<<dim3(JCAP, BATCH), 128, 0, stream>>>(Op, W, V);
  f_route <<<dim3(NT, BATCH), 256, 0, stream>>>(u, V, W, Op);
  f_makeV <<<dim3(JCAP, BATCH), 128, 0, stream>>>(Op, W, V);
  f_route <<<dim3(NT, BATCH), 256, 0, stream>>>(u, V, W, Op);
  f_squash<<<BATCH, 192, 0, stream>>>(Op, out);
}

// Round 2
// 180.938 us; speedup vs baseline: 1.1146x; 1.1146x over previous
//
#include <hip/hip_runtime.h>
#include <math.h>

// Capsule dynamic routing, MI355X. Round 7: occupancy-first route kernel.
// R6 post-mortem: route was latency-bound (Occ 17%, VALU 30%, HBM 8%) because
// 55.8KB LDS -> 2 blocks/CU and 7 barrier-separated phases had nothing to
// overlap with. R7: TROW 32 (u tile 16KB), V staged to LDS (broadcast reads),
// phase-1 partials pre-reduced in-register (shfl_xor 32), phase-2 waves own
// disjoint j-subsets over ALL rows (complete G, no cross-wave fold), G padded
// to stride 132 for bank-free W-fold. LDS 28.1KB -> 5 blocks/CU, 20 waves/CU.

#define BATCH 64
#define NN    2048
#define KD    128
#define JCAP  10
#define DCAP  16
#define JDIM  160
#define EPSQ  1e-7f
#define NT    64      // tiles of TROW rows
#define TROW  32
#define GSTR  132     // padded k-stride of G in LDS (banks j*4+k)

// ws layout (floats): Op[64][64][160] @0 ; V[64][10][128] @655360
#define WS_OP 0
#define WS_V  (BATCH * NT * JDIM)

__device__ __forceinline__ void gload16(const float* g, void* l) {
  __builtin_amdgcn_global_load_lds(
      (const __attribute__((address_space(1))) void*)g,
      (__attribute__((address_space(3))) void*)l, 16, 0, 0);
}

// ---- K1: iteration 0 (c uniform 0.1): per-tile colsum -> fold through W ----
__global__ __launch_bounds__(256) void f_iter0(const float* __restrict__ u,
                                               const float* __restrict__ W,
                                               float* __restrict__ Op) {
  const int b = blockIdx.y, tile = blockIdx.x, t = threadIdx.x;
  __shared__ __align__(16) float4 red[256];
  __shared__ float S_s[KD];
  const int c = t & 31, rg = t >> 5;        // 8 row-groups x 4 rows
  const float* p = u + (((size_t)(b * NN + tile * TROW + rg * 4)) << 7) + (c << 2);
  float4 a = make_float4(0.f, 0.f, 0.f, 0.f);
#pragma unroll
  for (int r = 0; r < 4; ++r) {
    const float4 w4 = *(const float4*)(p + ((size_t)r << 7));
    a.x += w4.x; a.y += w4.y; a.z += w4.z; a.w += w4.w;
  }
  red[t] = a;
  __syncthreads();
  if (t < 32) {
    float4 s4 = red[t];
#pragma unroll
    for (int g = 1; g < 8; ++g) {
      const float4 w4 = red[g * 32 + t];
      s4.x += w4.x; s4.y += w4.y; s4.z += w4.z; s4.w += w4.w;
    }
    s4.x *= 0.1f; s4.y *= 0.1f; s4.z *= 0.1f; s4.w *= 0.1f;
    *(float4*)&S_s[t * 4] = s4;              // G[j][k] = 0.1*S[k] for all j
  }
  __syncthreads();
  if (t < JDIM) {
    float acc = 0.f;
#pragma unroll 4
    for (int k = 0; k < KD; ++k) acc += S_s[k] * W[k * JDIM + t];
    Op[((size_t)(b * NT) + tile) * JDIM + t] = acc;
  }
}

// ---- K2/K4: fold Op -> o[b,j,:] -> V[b,j,:] ; grid (10, 64), 128 thr ----
__global__ __launch_bounds__(128) void f_makeV(const float* __restrict__ Op,
                                               const float* __restrict__ W,
                                               float* __restrict__ V) {
  const int j = blockIdx.x, b = blockIdx.y, t = threadIdx.x;
  __shared__ float o_s[DCAP];
  if (t < DCAP) {
    float s = 0.f;
    const float* p = Op + (size_t)b * NT * JDIM + j * DCAP + t;
#pragma unroll
    for (int tl = 0; tl < NT; ++tl) s += p[tl * JDIM];
    o_s[t] = s;
  }
  __syncthreads();
  const float* wp = W + t * JDIM + j * DCAP;   // t = k (0..127)
  float acc = 0.f;
#pragma unroll
  for (int d = 0; d < DCAP; ++d) acc += wp[d] * o_s[d];
  V[((size_t)(b * JCAP + j) << 7) + t] = acc;
}

// ---- K3/K5: full routing iteration: logits -> softmax -> G -> fold W ----
__global__ __launch_bounds__(256) void f_route(const float* __restrict__ u,
                                               const float* __restrict__ V,
                                               const float* __restrict__ W,
                                               float* __restrict__ Op) {
  const int b = blockIdx.y, tile = blockIdx.x, t = threadIdx.x;
  const int r0 = tile * TROW;
  __shared__ __align__(16) float4 u4[TROW * 32];    // 16 KB, XOR-swizzled
  __shared__ __align__(16) float4 Vs4[JCAP * 32];   // 5 KB, linear
  __shared__ __align__(16) float Cs[JCAP][TROW];    // 1.25 KB
  __shared__ __align__(16) float GpPl[JCAP * GSTR]; // 5.28 KB (ph1: Pl[4][10][32])

  // stage u tile (swizzled source, linear dest) + V (linear) via DMA
  {
    const float* ub = u + (((size_t)(b * NN + r0)) << 7);
    const int wbase = t & 192;                      // wave base within block
#pragma unroll
    for (int p = 0; p < 4; ++p) {
      const int s = p * 256 + t;
      const int r = s >> 5, csl = s & 31;
      const int c = csl ^ (r & 7);                  // involution
      gload16(ub + (((size_t)r) << 7) + (c << 2), &u4[p * 256 + wbase]);
    }
    const float* vb = V + (((size_t)(b * JCAP)) << 7);
    gload16(vb + (t << 2), &Vs4[wbase]);
    if (t < 64) gload16(vb + ((256 + t) << 2), &Vs4[256]);
  }
  __syncthreads();   // drains vmcnt

  // phase 1: logits. thread = (row r, k-eighth q8); V reads are broadcasts.
  {
    const int r = t & 31, q8 = t >> 5;
    float acc[JCAP];
#pragma unroll
    for (int j = 0; j < JCAP; ++j) acc[j] = 0.f;
#pragma unroll
    for (int c4 = 0; c4 < 4; ++c4) {
      const float4 uu = u4[(r << 5) + ((q8 * 4 + c4) ^ (r & 7))];
#pragma unroll
      for (int j = 0; j < JCAP; ++j) {
        const float4 vv = Vs4[j * 32 + q8 * 4 + c4];
        acc[j] += uu.x * vv.x + uu.y * vv.y + uu.z * vv.z + uu.w * vv.w;
      }
    }
    // in-register pre-reduce: lane l and l^32 hold adjacent k-eighths
#pragma unroll
    for (int j = 0; j < JCAP; ++j) acc[j] += __shfl_xor(acc[j], 32, 64);
    if ((t & 32) == 0) {
      const int q4 = t >> 6;                        // wave id = k-quarter
#pragma unroll
      for (int j = 0; j < JCAP; ++j) GpPl[(q4 * JCAP + j) * TROW + r] = acc[j];
    }
  }
  __syncthreads();
  if (t < TROW) {                                   // softmax over j
    float lg[JCAP];
    float m = -1e30f;
#pragma unroll
    for (int j = 0; j < JCAP; ++j) {
      const float s = GpPl[j * TROW + t] + GpPl[(JCAP + j) * TROW + t]
                    + GpPl[(2 * JCAP + j) * TROW + t]
                    + GpPl[(3 * JCAP + j) * TROW + t];
      lg[j] = s; m = fmaxf(m, s);
    }
    float ssum = 0.f;
#pragma unroll
    for (int j = 0; j < JCAP; ++j) { lg[j] = __expf(lg[j] - m); ssum += lg[j]; }
    const float inv = 1.f / ssum;
#pragma unroll
    for (int j = 0; j < JCAP; ++j) Cs[j][t] = lg[j] * inv;
  }
  __syncthreads();

  // phase 2: G[j][k] = sum_r c[j][r]*u[r][k]. Wave owns a j-subset over ALL
  // rows -> complete G, no cross-wave fold. lane = k-pair (b64 LDS reads).
  {
    const int w = t >> 6, l = t & 63;
    const int j0 = (w < 2) ? 3 * w : 2 * w + 2;     // {0,3,6,8}
    const int jn = (w < 2) ? 3 : 2;                 // {3,3,2,2}
    const int chalf = l >> 1, cin = (l & 1) << 1;   // k = 2*l
    float g0[3], g1[3];
#pragma unroll
    for (int jj = 0; jj < 3; ++jj) { g0[jj] = 0.f; g1[jj] = 0.f; }
    for (int rc = 0; rc < TROW; rc += 4) {
      float ua[4], uc[4];
#pragma unroll
      for (int qq = 0; qq < 4; ++qq) {
        const int r = rc + qq;
        const float2 uu2 =
            *(const float2*)((const float*)&u4[(r << 5) + (chalf ^ (r & 7))] + cin);
        ua[qq] = uu2.x; uc[qq] = uu2.y;
      }
#pragma unroll
      for (int jj = 0; jj < 3; ++jj) {
        if (jj < jn) {
          const float4 c4v = *(const float4*)&Cs[j0 + jj][rc];
          g0[jj] += c4v.x * ua[0] + c4v.y * ua[1] + c4v.z * ua[2] + c4v.w * ua[3];
          g1[jj] += c4v.x * uc[0] + c4v.y * uc[1] + c4v.z * uc[2] + c4v.w * uc[3];
        }
      }
    }
#pragma unroll
    for (int jj = 0; jj < 3; ++jj)
      if (jj < jn)
        *(float2*)&GpPl[(j0 + jj) * GSTR + 2 * l] = make_float2(g0[jj], g1[jj]);
  }
  __syncthreads();
  // fold G through W -> per-tile o partials (GSTR pad spreads j over banks)
  if (t < JDIM) {
    const int j = t >> 4;
    const float* gj = GpPl + j * GSTR;
    float acc = 0.f;
#pragma unroll 4
    for (int k = 0; k < KD; ++k) acc += gj[k] * W[k * JDIM + t];
    Op[((size_t)(b * NT) + tile) * JDIM + t] = acc;
  }
}

// ---- K6: fold Op partials, squash, store ----
__global__ __launch_bounds__(192) void f_squash(const float* __restrict__ Op,
                                                float* __restrict__ out) {
  const int b = blockIdx.x, t = threadIdx.x;
  __shared__ float o_s[JDIM];
  __shared__ float sc[JCAP];
  if (t < JDIM) {
    float s = 0.f;
    const float* p = Op + (size_t)b * NT * JDIM + t;
#pragma unroll
    for (int tl = 0; tl < NT; ++tl) s += p[tl * JDIM];
    o_s[t] = s;
  }
  __syncthreads();
  if (t < JCAP) {
    float s2 = 0.f;
#pragma unroll
    for (int d = 0; d < DCAP; ++d) { const float x = o_s[t * DCAP + d]; s2 += x * x; }
    sc[t] = s2 / ((1.f + s2) * sqrtf(s2 + EPSQ));
  }
  __syncthreads();
  if (t < JDIM) out[b * JDIM + t] = o_s[t] * sc[t >> 4];
}

extern "C" void kernel_launch(void* const* d_in, const int* in_sizes, int n_in,
                              void* d_out, int out_size, void* d_ws, size_t ws_size,
                              hipStream_t stream) {
  const float* u = (const float*)d_in[0];   // (64,2048,128) fp32
  const float* W = (const float*)d_in[1];   // (128,160) fp32
  float* out = (float*)d_out;               // (64,10,16) fp32
  float* ws  = (float*)d_ws;

  float* Op = ws + WS_OP;
  float* V  = ws + WS_V;
  f_iter0 <<<dim3(NT, BATCH), 256, 0, stream>>>(u, W, Op);
  f_makeV <<<dim3(JCAP, BATCH), 128, 0, stream>>>(Op, W, V);
  f_route <<<dim3(NT, BATCH), 256, 0, stream>>>(u, V, W, Op);
  f_makeV <<<dim3(JCAP, BATCH), 128, 0, stream>>>(Op, W, V);
  f_route <<<dim3(NT, BATCH), 256, 0, stream>>>(u, V, W, Op);
  f_squash<<<BATCH, 192, 0, stream>>>(Op, out);
}